// Round 18
// baseline (419.522 us; speedup 1.0000x reference)
//
#include <hip/hip_runtime.h>
#include <cmath>

#define THREADS 256

static constexpr int N_NODES   = 100000;
static constexpr int N_EDGES   = 800000;
static constexpr int NIN       = 40000;   // input_mask: n < NIN
static constexpr int NOUT_BASE = 60000;   // output_mask: n >= NOUT_BASE
static constexpr int NOUT      = 40000;
static constexpr int LIST_CAP  = 400000;
static constexpr int PAD       = 16;      // u32 per bin (64B line) for contention-free atomics

// ---- workspace layout (32-bit words), ~45 MB ----
static constexpr size_t OFF_NFI   = 0;                                // 40000*64 f32 (pre-composed ri-l0 sums)
static constexpr size_t OFF_F1    = OFF_NFI   + (size_t)NIN  * 64;    // 40000*32 f32
static constexpr size_t OFF_F2    = OFF_F1    + (size_t)NOUT * 32;    // 40000*32 u32 keys
static constexpr size_t OFF_HPO   = OFF_F2    + (size_t)NOUT * 32;    // 40000*PAD u32 padded hist (o)
static constexpr size_t OFF_HPI   = OFF_HPO   + (size_t)NIN  * PAD;   // 40000*PAD u32 padded hist (i)
static constexpr size_t OFF_ZEND  = OFF_HPI   + (size_t)NOUT * PAD;   // zeroed region end
static constexpr size_t OFF_CNT   = OFF_ZEND;                         // 40000 u32 (dst_in deg, scan-written)
static constexpr size_t OFF_CNTO  = OFF_CNT   + NOUT;                 // 40000 u32 (dst_out deg, scan-written)
static constexpr size_t OFF_CTRO  = OFF_CNTO  + NIN;                  // 1
static constexpr size_t OFF_CTRI  = OFF_CTRO  + 1;                    // 1
static constexpr size_t OFF_BVEC  = OFF_CTRI  + 1;                    // 64 f32 (b4 @ Wr)
static constexpr size_t OFF_OPO   = OFF_BVEC + 64;                    // 40000*PAD u32 padded offs (o)
static constexpr size_t OFF_OPI   = OFF_OPO + (size_t)NIN * PAD;      // 40000*PAD u32 padded offs (i)
static constexpr size_t OFF_LISTO = (OFF_OPI + (size_t)NOUT * PAD + 1) & ~(size_t)1; // LIST_CAP uint2
static constexpr size_t OFF_LISTI = OFF_LISTO + 2 * (size_t)LIST_CAP; // LIST_CAP uint2
static constexpr size_t OFF_WB    = (OFF_LISTI + 2 * (size_t)LIST_CAP + 3) & ~(size_t)3;  // 47936 u32
static constexpr size_t OFF_NFB   = OFF_WB + 47936;                   // nf bf16: 1.6M u32

// converted-weight offsets (ushort units). [n][k] layout, strides = Kp+8 (bank pad)
static constexpr unsigned OW_O2I0  = 0;       // 64 x 168
static constexpr unsigned OW_O2I1  = 10752;   // 64 x 72
static constexpr unsigned OW_O2I2  = 15360;
static constexpr unsigned OW_O2I3  = 19968;
static constexpr unsigned OW_O2I4C = 24576;   // 64 x 72  (composed o2i_w4 @ ri_w0[64:192])
static constexpr unsigned OW_I2O0  = 29184;   // 64 x 168
static constexpr unsigned OW_I2O1  = 39936;
static constexpr unsigned OW_I2O2  = 44544;
static constexpr unsigned OW_I2O3  = 49152;   // 80 x 72 (N=65 padded)
static constexpr unsigned OW_RI0   = 54912;   // 64 x 72 (nf part only: ri_w0[0:64])
static constexpr unsigned OW_RI1   = 59520;
static constexpr unsigned OW_RI2   = 64128;
static constexpr unsigned OW_RI3   = 68736;
static constexpr unsigned OW_RO0   = 73344;   // 64 x 136
static constexpr unsigned OW_RO1   = 82048;
static constexpr unsigned OW_RO2   = 86656;
static constexpr unsigned OW_RO3   = 91264;   // end 95872

typedef __attribute__((ext_vector_type(8))) short short8;
typedef __attribute__((ext_vector_type(4))) float f32x4;

__device__ __forceinline__ float lrelu(float x) { return x > 0.0f ? x : 0.2f * x; }

__device__ __forceinline__ unsigned short f2b(float f) {   // RNE f32->bf16
    unsigned u = __float_as_uint(f);
    return (unsigned short)((u + 0x7fffu + ((u >> 16) & 1u)) >> 16);
}
__device__ __forceinline__ unsigned pk2(float a, float b) {
    return (unsigned)f2b(a) | ((unsigned)f2b(b) << 16);
}
__device__ __forceinline__ short8 cvt8(const float4 va, const float4 vb) {
    union { uint4 u; short8 s; } t;
    t.u = make_uint4(pk2(va.x, va.y), pk2(va.z, va.w), pk2(vb.x, vb.y), pk2(vb.z, vb.w));
    return t.s;
}
__device__ __forceinline__ unsigned fkey(float f) {
    unsigned u = __float_as_uint(f);
    return (u & 0x80000000u) ? ~u : (u | 0x80000000u);
}
__device__ __forceinline__ float funkey(unsigned k) {
    return (k & 0x80000000u) ? __uint_as_float(k & 0x7fffffffu) : __uint_as_float(~k);
}
__device__ __forceinline__ uint2 packm(unsigned s, int d, int e) {
    return make_uint2(s | ((unsigned)(d & 0x7FFF) << 17),
                      (unsigned)e | (((unsigned)d >> 15) << 20));
}

// ---- block-cooperative gemm (node kernels) ----
template<int MT, int NT, int KT, int XSTR, int WSTR>
__device__ __forceinline__ void gemm_core(const unsigned short* X, const unsigned short* W,
                                          const float* bias, int biasN, int wv, int lane,
                                          f32x4 (&acc)[MT][NT]) {
    const int r = lane & 15, kg = lane >> 4;
    short8 a[MT][KT];
#pragma unroll
    for (int mt = 0; mt < MT; ++mt)
#pragma unroll
        for (int kk = 0; kk < KT; ++kk)
            a[mt][kk] = *(const short8*)(X + (wv * 16 * MT + mt * 16 + r) * XSTR + kk * 32 + kg * 8);
#pragma unroll
    for (int nt = 0; nt < NT; ++nt) {
        const int c = nt * 16 + r;
        const float bv = (c < biasN) ? bias[c] : 0.0f;
#pragma unroll
        for (int mt = 0; mt < MT; ++mt) acc[mt][nt] = (f32x4){bv, bv, bv, bv};
    }
#pragma unroll
    for (int kk = 0; kk < KT; ++kk)
#pragma unroll
        for (int nt = 0; nt < NT; ++nt) {
            short8 b = *(const short8*)(W + (nt * 16 + r) * WSTR + kk * 32 + kg * 8);
#pragma unroll
            for (int mt = 0; mt < MT; ++mt)
                acc[mt][nt] = __builtin_amdgcn_mfma_f32_16x16x32_bf16(a[mt][kk], b, acc[mt][nt], 0, 0, 0);
        }
}

template<int MT, int NT, int XSTR>
__device__ __forceinline__ void writeback(unsigned short* X, f32x4 (&acc)[MT][NT], int wv, int lane) {
    const int r = lane & 15, kg = lane >> 4;
#pragma unroll
    for (int mt = 0; mt < MT; ++mt)
#pragma unroll
        for (int nt = 0; nt < NT; ++nt)
#pragma unroll
            for (int q = 0; q < 4; ++q)
                X[(wv * 16 * MT + mt * 16 + kg * 4 + q) * XSTR + nt * 16 + r] = f2b(lrelu(acc[mt][nt][q]));
}

// ---- wave-local gemm (edge kernels) ----
template<int NT, int KT, int XSTR, int WSTR>
__device__ __forceinline__ void gemm_w1(const unsigned short* Xw, const unsigned short* W,
                                        const float* bv, int lane, f32x4 (&acc)[NT]) {
    const int r = lane & 15, kg = lane >> 4;
    short8 a[KT];
#pragma unroll
    for (int kk = 0; kk < KT; ++kk)
        a[kk] = *(const short8*)(Xw + r * XSTR + kk * 32 + kg * 8);
#pragma unroll
    for (int nt = 0; nt < NT; ++nt) acc[nt] = (f32x4){bv[nt], bv[nt], bv[nt], bv[nt]};
#pragma unroll
    for (int kk = 0; kk < KT; ++kk)
#pragma unroll
        for (int nt = 0; nt < NT; ++nt) {
            short8 b = *(const short8*)(W + (nt * 16 + r) * WSTR + kk * 32 + kg * 8);
            acc[nt] = __builtin_amdgcn_mfma_f32_16x16x32_bf16(a[kk], b, acc[nt], 0, 0, 0);
        }
}

template<int NT, int XSTR>
__device__ __forceinline__ void writeback_w1(unsigned short* Xw, f32x4 (&acc)[NT], int lane) {
    const int r = lane & 15, kg = lane >> 4;
#pragma unroll
    for (int nt = 0; nt < NT; ++nt)
#pragma unroll
        for (int q = 0; q < 4; ++q)
            Xw[(kg * 4 + q) * XSTR + nt * 16 + r] = f2b(lrelu(acc[nt][q]));
}

// ---- weight conversion ----
struct WDesc { const float* w; int K, N, stride, Np; unsigned off; };
struct WTab { WDesc d[16]; };

__global__ __launch_bounds__(THREADS)
void convert_w(WTab t, unsigned short* wts) {
    const WDesc d = t.d[blockIdx.y];
    const int idx = blockIdx.x * THREADS + threadIdx.x;
    const int tot = d.Np * d.stride;
    if (idx >= tot) return;
    const int n = idx / d.stride, k = idx - n * d.stride;
    const float v = (k < d.K && n < d.N) ? d.w[(size_t)k * d.N + n] : 0.0f;
    wts[d.off + idx] = f2b(v);
}

// ---- compose Wc = o2i_w4 (64x128) @ ri_w0[64:192] (128x64) -> bf16 [n][72]; bvec = b4 @ Wr ----
__global__ __launch_bounds__(THREADS)
void compose_k(const float* __restrict__ w4, const float* __restrict__ rw0,
               const float* __restrict__ b4, unsigned short* __restrict__ wts,
               float* __restrict__ bvec) {
    const int idx = blockIdx.x * THREADS + threadIdx.x;
    if (idx < 4096) {
        const int n = idx >> 6, k = idx & 63;
        float s = 0.0f;
        for (int j = 0; j < 128; ++j) s += w4[k * 128 + j] * rw0[(size_t)(64 + j) * 64 + n];
        wts[OW_O2I4C + n * 72 + k] = f2b(s);
    } else if (idx < 4160) {
        const int n = idx - 4096;
        float s = 0.0f;
        for (int j = 0; j < 128; ++j) s += b4[j] * rw0[(size_t)(64 + j) * 64 + n];
        bvec[n] = s;
    }
}

// ---- nf -> bf16 table ----
__global__ __launch_bounds__(THREADS)
void conv_nf_k(const float* __restrict__ nf, unsigned short* __restrict__ nfb) {
    const int i = blockIdx.x * THREADS + threadIdx.x;
    if (i >= N_NODES * 8) return;
    const float4 va = ((const float4*)nf)[i * 2], vb = ((const float4*)nf)[i * 2 + 1];
    *(uint4*)(nfb + (size_t)i * 8) =
        make_uint4(pk2(va.x, va.y), pk2(va.z, va.w), pk2(vb.x, vb.y), pk2(vb.z, vb.w));
}

// ---- counting sort phase 1: padded per-dst histograms (1 bin per 64B line) ----
__global__ __launch_bounds__(THREADS)
void hist_k(const int* __restrict__ dst_out, const int* __restrict__ dst_in,
            unsigned* __restrict__ hpo, unsigned* __restrict__ hpi) {
    const int e = blockIdx.x * THREADS + threadIdx.x;   // grid covers N_EDGES exactly
    const int d0 = dst_out[e];
    if (d0 < NIN) atomicAdd(hpo + (size_t)d0 * PAD, 1u);
    const int d1 = dst_in[e];
    if (d1 >= NOUT_BASE) atomicAdd(hpi + (size_t)(d1 - NOUT_BASE) * PAD, 1u);
}

// ---- counting sort phase 2: scan padded hist -> padded offs + compact counts ----
__global__ __launch_bounds__(1024)
void scan2_k(const unsigned* __restrict__ hpo, const unsigned* __restrict__ hpi,
             unsigned* __restrict__ opo, unsigned* __restrict__ opi,
             unsigned* __restrict__ cnto, unsigned* __restrict__ cnt,
             unsigned* __restrict__ ctro, unsigned* __restrict__ ctri) {
    const unsigned* h = (blockIdx.x == 0) ? hpo : hpi;
    unsigned* o       = (blockIdx.x == 0) ? opo : opi;
    unsigned* cc      = (blockIdx.x == 0) ? cnto : cnt;
    unsigned* tot     = (blockIdx.x == 0) ? ctro : ctri;
    const int tid = threadIdx.x, lane = tid & 63, wv = tid >> 6;
    const int lo = tid * 40;
    const int hi = (lo + 40 < NIN) ? lo + 40 : NIN;
    unsigned s = 0;
    for (int i = lo; i < hi; ++i) s += h[(size_t)i * PAD];
    unsigned incl = s;
    for (int d = 1; d < 64; d <<= 1) { unsigned v = __shfl_up(incl, d); if (lane >= d) incl += v; }
    __shared__ unsigned wsum[16], woff[16];
    if (lane == 63) wsum[wv] = incl;
    __syncthreads();
    if (tid < 16) {
        unsigned v = wsum[tid], sc = v;
        for (int d = 1; d < 16; d <<= 1) { unsigned t2 = __shfl_up(sc, d); if (tid >= d) sc += t2; }
        woff[tid] = sc - v;
    }
    __syncthreads();
    unsigned run = woff[wv] + incl - s;
    for (int i = lo; i < hi; ++i) {
        const unsigned c = h[(size_t)i * PAD];
        cc[i] = c;
        o[(size_t)i * PAD] = run;
        run += c;
    }
    if (hi == NIN && lo < NIN) *tot = run;
}

// ---- counting sort phase 3: emit dst-sorted packed lists {src,dst,e} (padded offset bins) ----
__global__ __launch_bounds__(THREADS)
void emit_k(const int* __restrict__ src_out, const int* __restrict__ dst_out,
            const int* __restrict__ src_in, const int* __restrict__ dst_in,
            unsigned* __restrict__ opo, unsigned* __restrict__ opi,
            uint2* __restrict__ listo, uint2* __restrict__ listi) {
    const int e = blockIdx.x * THREADS + threadIdx.x;
    const int d0 = dst_out[e];
    if (d0 < NIN) {
        const unsigned p = atomicAdd(opo + (size_t)d0 * PAD, 1u);
        if (p < (unsigned)LIST_CAP) listo[p] = packm((unsigned)src_out[e], d0, e);
    }
    const int d1 = dst_in[e];
    if (d1 >= NOUT_BASE) {
        const unsigned p = atomicAdd(opi + (size_t)(d1 - NOUT_BASE) * PAD, 1u);
        if (p < (unsigned)LIST_CAP) listi[p] = packm((unsigned)src_in[e], d1, e);
    }
}

// gather layer-0 A-fragments: src/dst rows from bf16 table, ef from f32
__device__ __forceinline__ void gather_a(short8 (&a)[5], const unsigned short* nfb, const float* ef,
                                         int e16, int s16, int d16, int kg) {
    const short8 z = {0, 0, 0, 0, 0, 0, 0, 0};
    if (e16 >= 0) {
        const unsigned short* ps = nfb + (size_t)s16 * 64 + kg * 8;
        const unsigned short* pd = nfb + (size_t)d16 * 64 + kg * 8;
        a[0] = *(const short8*)ps;
        a[1] = *(const short8*)(ps + 32);
        a[2] = *(const short8*)pd;
        a[3] = *(const short8*)(pd + 32);
        if (kg < 2) {
            const float* pe = ef + (size_t)e16 * 16 + kg * 8;
            a[4] = cvt8(((const float4*)pe)[0], ((const float4*)pe)[1]);
        } else a[4] = z;
    } else { a[0] = z; a[1] = z; a[2] = z; a[3] = z; a[4] = z; }
}

// ---- o2i edge MLP: composed last layer (64-wide), dst-sorted run-aggregated scatter ----
__global__ __launch_bounds__(512, 4)
void edge_out_mfma(const unsigned short* __restrict__ nfb, const float* __restrict__ ef,
                   const uint2* __restrict__ list, const unsigned* __restrict__ counter,
                   const unsigned short* __restrict__ wts,
                   const float* __restrict__ b0, const float* __restrict__ b1,
                   const float* __restrict__ b2, const float* __restrict__ b3,
                   float* __restrict__ nfi) {
    __shared__ unsigned short W[24576];     // layers 0-3
    __shared__ unsigned short X[128 * 72];
    const int tid = threadIdx.x, lane = tid & 63, wv = tid >> 6;
    const int r = lane & 15, kg = lane >> 4;
    for (int i = tid * 8; i < 24576; i += 512 * 8)
        *(uint4*)(W + i) = *(const uint4*)(wts + OW_O2I0 + i);
    float bv0[4], bv1[4], bv2[4], bv3[4];
    const float bz[4] = {0.0f, 0.0f, 0.0f, 0.0f};
#pragma unroll
    for (int nt = 0; nt < 4; ++nt) {
        bv0[nt] = b0[nt * 16 + r]; bv1[nt] = b1[nt * 16 + r];
        bv2[nt] = b2[nt * 16 + r]; bv3[nt] = b3[nt * 16 + r];
    }
    unsigned short* Xw = X + wv * 16 * 72;
    const unsigned short* W4C = wts + OW_O2I4C;   // 9.2KB composed weights, L1-resident
    const unsigned total = *counter;
    const unsigned nchunks = (total + 15) >> 4;
    __syncthreads();

    for (unsigned c = blockIdx.x * 8 + wv; c < nchunks; c += (unsigned)gridDim.x * 8) {
        const unsigned ebase = c << 4;
        int my_e = -1, my_s = 0, my_d = -1;
        if (lane < 16 && ebase + (unsigned)lane < total) {
            const uint2 m = list[ebase + lane];
            my_s = (int)(m.x & 0x1FFFFu);
            my_d = (int)(((m.x >> 17) & 0x7FFFu) | (((m.y >> 20) & 3u) << 15));
            my_e = (int)(m.y & 0xFFFFFu);
        }
        const int e16 = __shfl(my_e, r), s16 = __shfl(my_s, r), d16 = __shfl(my_d, r);
        short8 a[5];
        gather_a(a, nfb, ef, e16, s16, d16, kg);
        f32x4 acc[4];
#pragma unroll
        for (int nt = 0; nt < 4; ++nt) acc[nt] = (f32x4){bv0[nt], bv0[nt], bv0[nt], bv0[nt]};
#pragma unroll
        for (int kk = 0; kk < 5; ++kk)
#pragma unroll
            for (int nt = 0; nt < 4; ++nt) {
                short8 b = *(const short8*)(W + (nt * 16 + r) * 168 + kk * 32 + kg * 8);
                acc[nt] = __builtin_amdgcn_mfma_f32_16x16x32_bf16(a[kk], b, acc[nt], 0, 0, 0);
            }
        writeback_w1<4, 72>(Xw, acc, lane);
        gemm_w1<4, 2, 72, 72>(Xw, W + 10752, bv1, lane, acc); writeback_w1<4, 72>(Xw, acc, lane);
        gemm_w1<4, 2, 72, 72>(Xw, W + 15360, bv2, lane, acc); writeback_w1<4, 72>(Xw, acc, lane);
        gemm_w1<4, 2, 72, 72>(Xw, W + 19968, bv3, lane, acc); writeback_w1<4, 72>(Xw, acc, lane);
        f32x4 acc4[4];
        gemm_w1<4, 2, 72, 72>(Xw, W4C, bz, lane, acc4);
        // per-kg run-aggregated scatter-add (sorted list -> runs aggregate; 4 lines per flush)
        int re[4], rd[4];
#pragma unroll
        for (int q = 0; q < 4; ++q) {
            re[q] = __shfl(my_e, kg * 4 + q);
            rd[q] = __shfl(my_d, kg * 4 + q);
        }
        float s[4];
        int cur = -1;
#pragma unroll
        for (int q = 0; q < 4; ++q) {
            if (re[q] < 0) break;
            if (rd[q] != cur) {
                if (cur >= 0) {
                    float* p = nfi + (size_t)cur * 64;
#pragma unroll
                    for (int nt = 0; nt < 4; ++nt) atomicAdd(p + nt * 16 + r, s[nt]);
                }
                cur = rd[q];
#pragma unroll
                for (int nt = 0; nt < 4; ++nt) s[nt] = acc4[nt][q];
            } else {
#pragma unroll
                for (int nt = 0; nt < 4; ++nt) s[nt] += acc4[nt][q];
            }
        }
        if (cur >= 0) {
            float* p = nfi + (size_t)cur * 64;
#pragma unroll
            for (int nt = 0; nt < 4; ++nt) atomicAdd(p + nt * 16 + r, s[nt]);
        }
    }
}

// ---- i2o edge MLP: dst-sorted run-aggregated gated scatter ----
__global__ __launch_bounds__(512, 4)
void edge_in_mfma(const unsigned short* __restrict__ nfb, const float* __restrict__ ef,
                  const uint2* __restrict__ list, const unsigned* __restrict__ counter,
                  const unsigned short* __restrict__ wts,
                  const float* __restrict__ b0, const float* __restrict__ b1,
                  const float* __restrict__ b2, const float* __restrict__ b3,
                  float* __restrict__ f1s, unsigned* __restrict__ f2k) {
    __shared__ unsigned short W[25728];
    __shared__ unsigned short X[128 * 72];
    const int tid = threadIdx.x, lane = tid & 63, wv = tid >> 6;
    const int r = lane & 15, kg = lane >> 4;
    for (int i = tid * 8; i < 25728; i += 512 * 8)
        *(uint4*)(W + i) = *(const uint4*)(wts + OW_I2O0 + i);
    float bv0[4], bv1[4], bv2[4], bv3[5];
#pragma unroll
    for (int nt = 0; nt < 4; ++nt) {
        bv0[nt] = b0[nt * 16 + r]; bv1[nt] = b1[nt * 16 + r]; bv2[nt] = b2[nt * 16 + r];
        bv3[nt] = b3[nt * 16 + r];
    }
    bv3[4] = (r == 0) ? b3[64] : 0.0f;
    unsigned short* Xw = X + wv * 16 * 72;
    const unsigned total = *counter;
    const unsigned nchunks = (total + 15) >> 4;
    bool valid[5], isadd[5];
#pragma unroll
    for (int nt = 0; nt < 5; ++nt) {
        const int cc = nt * 16 + r;
        valid[nt] = (cc >= 1 && cc <= 64);
        isadd[nt] = (cc <= 32);
    }
    __syncthreads();

    for (unsigned c = blockIdx.x * 8 + wv; c < nchunks; c += (unsigned)gridDim.x * 8) {
        const unsigned ebase = c << 4;
        int my_e = -1, my_s = 0, my_d = -1;
        if (lane < 16 && ebase + (unsigned)lane < total) {
            const uint2 m = list[ebase + lane];
            my_s = (int)(m.x & 0x1FFFFu);
            my_d = (int)(((m.x >> 17) & 0x7FFFu) | (((m.y >> 20) & 3u) << 15));
            my_e = (int)(m.y & 0xFFFFFu);
        }
        const int e16 = __shfl(my_e, r), s16 = __shfl(my_s, r), d16 = __shfl(my_d, r);
        short8 a[5];
        gather_a(a, nfb, ef, e16, s16, d16, kg);
        f32x4 acc[4];
#pragma unroll
        for (int nt = 0; nt < 4; ++nt) acc[nt] = (f32x4){bv0[nt], bv0[nt], bv0[nt], bv0[nt]};
#pragma unroll
        for (int kk = 0; kk < 5; ++kk)
#pragma unroll
            for (int nt = 0; nt < 4; ++nt) {
                short8 b = *(const short8*)(W + (nt * 16 + r) * 168 + kk * 32 + kg * 8);
                acc[nt] = __builtin_amdgcn_mfma_f32_16x16x32_bf16(a[kk], b, acc[nt], 0, 0, 0);
            }
        writeback_w1<4, 72>(Xw, acc, lane);
        gemm_w1<4, 2, 72, 72>(Xw, W + 10752, bv1, lane, acc); writeback_w1<4, 72>(Xw, acc, lane);
        gemm_w1<4, 2, 72, 72>(Xw, W + 15360, bv2, lane, acc); writeback_w1<4, 72>(Xw, acc, lane);
        f32x4 acc5[5];
        gemm_w1<5, 2, 72, 72>(Xw, W + 19968, bv3, lane, acc5);
        int re[4], rd[4];
        float rgv[4];
#pragma unroll
        for (int q = 0; q < 4; ++q) {
            re[q]  = __shfl(my_e, kg * 4 + q);
            rd[q]  = __shfl(my_d, kg * 4 + q);
            rgv[q] = __shfl(acc5[4][q], lane & 48);
        }
        float s[5];
        int cur = -1;
        auto flush = [&](int d) {
            if (d < 0) return;
            const int rr = d - NOUT_BASE;
            if (valid[0]) atomicAdd(f1s + (size_t)rr * 32 + (r - 1), s[0]);
            if (valid[1]) atomicAdd(f1s + (size_t)rr * 32 + 15 + r, s[1]);
            if (valid[2]) {
                if (isadd[2]) atomicAdd(f1s + (size_t)rr * 32 + 31, s[2]);
                else          atomicMax(f2k + (size_t)rr * 32 + (r - 1), fkey(s[2]));
            }
            if (valid[3]) atomicMax(f2k + (size_t)rr * 32 + 15 + r, fkey(s[3]));
            if (valid[4]) atomicMax(f2k + (size_t)rr * 32 + 31, fkey(s[4]));
        };
#pragma unroll
        for (int q = 0; q < 4; ++q) {
            if (re[q] < 0) break;
            const float kgv = 1.0f / (1.0f + expf(-rgv[q]));
            if (rd[q] != cur) {
                flush(cur);
                cur = rd[q];
#pragma unroll
                for (int nt = 0; nt < 5; ++nt) s[nt] = acc5[nt][q] * kgv;
            } else {
#pragma unroll
                for (int nt = 0; nt < 5; ++nt) {
                    const float v = acc5[nt][q] * kgv;
                    s[nt] = isadd[nt] ? s[nt] + v : fmaxf(s[nt], v);
                }
            }
        }
        flush(cur);
    }
}

// ---- ri node MLP: layer0 = nf@W0a + nfi_s + cnt*bvec + b0, then 64->64->64->64 ----
__global__ __launch_bounds__(THREADS)
void node_ri_mfma(const unsigned short* __restrict__ nfb, const float* __restrict__ nfi,
                  const unsigned* __restrict__ cnto, const float* __restrict__ bvec,
                  const unsigned short* __restrict__ wts,
                  const float* __restrict__ b0, const float* __restrict__ b1,
                  const float* __restrict__ b2, const float* __restrict__ b3,
                  float* __restrict__ out) {
    __shared__ unsigned short X[64 * 72];
    __shared__ unsigned short Wl[4608];
    const int tid = threadIdx.x, lane = tid & 63, wv = tid >> 6;
    const int base = blockIdx.x * 64;
    for (int i = tid; i < 64 * 8; i += THREADS) {
        const int el = i >> 3, q = i & 7;
        *(uint4*)(X + el * 72 + q * 8) = *(const uint4*)(nfb + (size_t)(base + el) * 64 + q * 8);
    }
    auto stage = [&](unsigned off) {
        for (int i = tid * 8; i < 4608; i += THREADS * 8)
            *(uint4*)(Wl + i) = *(const uint4*)(wts + off + i);
    };
    stage(OW_RI0);
    __syncthreads();
    const int r = lane & 15, kg = lane >> 4;
    f32x4 acc[1][4];
    gemm_core<1, 4, 2, 72, 72>(X, Wl, b0, 64, wv, lane, acc);
    {
        float bvv[4];
#pragma unroll
        for (int nt = 0; nt < 4; ++nt) bvv[nt] = bvec[nt * 16 + r];
#pragma unroll
        for (int q = 0; q < 4; ++q) {
            const int node = base + wv * 16 + kg * 4 + q;
            const float cf = (float)cnto[node];
#pragma unroll
            for (int nt = 0; nt < 4; ++nt)
                acc[0][nt][q] += nfi[(size_t)node * 64 + nt * 16 + r] + cf * bvv[nt];
        }
    }
    writeback<1, 4, 72>(X, acc, wv, lane);
    __syncthreads(); stage(OW_RI1); __syncthreads();
    gemm_core<1, 4, 2, 72, 72>(X, Wl, b1, 64, wv, lane, acc);
    writeback<1, 4, 72>(X, acc, wv, lane);
    __syncthreads(); stage(OW_RI2); __syncthreads();
    gemm_core<1, 4, 2, 72, 72>(X, Wl, b2, 64, wv, lane, acc);
    writeback<1, 4, 72>(X, acc, wv, lane);
    __syncthreads(); stage(OW_RI3); __syncthreads();
    gemm_core<1, 4, 2, 72, 72>(X, Wl, b3, 64, wv, lane, acc);
#pragma unroll
    for (int nt = 0; nt < 4; ++nt)
#pragma unroll
        for (int q = 0; q < 4; ++q)
            out[(size_t)(base + wv * 16 + kg * 4 + q) * 64 + nt * 16 + r] = acc[0][nt][q];
}

// ---- ro node MLP (128->64->64->64->64), nodes [NOUT_BASE, N) ----
__global__ __launch_bounds__(THREADS)
void node_ro_mfma(const float* __restrict__ nf, const float* __restrict__ f1s,
                  const unsigned* __restrict__ f2k, const unsigned* __restrict__ cnt,
                  const unsigned short* __restrict__ wts,
                  const float* __restrict__ b0, const float* __restrict__ b1,
                  const float* __restrict__ b2, const float* __restrict__ b3,
                  float* __restrict__ out) {
    __shared__ unsigned short X[64 * 136];
    __shared__ unsigned short Wl[8704];
    const int tid = threadIdx.x, lane = tid & 63, wv = tid >> 6;
    const int rbase = blockIdx.x * 64;
    for (int i = tid; i < 64 * 17; i += THREADS) {
        const int el = i / 17, q = i - el * 17;
        const int rr = rbase + el;
        unsigned p0 = 0, p1 = 0, p2 = 0, p3 = 0;
        if (q < 16) {
            float v[8];
            if (q < 8) {
                const float* sp = nf + (size_t)(NOUT_BASE + rr) * 64 + q * 8;
                const float4 va = *(const float4*)sp, vb = *(const float4*)(sp + 4);
                v[0]=va.x; v[1]=va.y; v[2]=va.z; v[3]=va.w; v[4]=vb.x; v[5]=vb.y; v[6]=vb.z; v[7]=vb.w;
            } else {
                const unsigned cc = cnt[rr];
                if (q < 12) {
                    const float inv = 1.0f / fmaxf((float)cc, 1.0f);
#pragma unroll
                    for (int j = 0; j < 8; ++j) v[j] = f1s[(size_t)rr * 32 + (q - 8) * 8 + j] * inv;
                } else {
#pragma unroll
                    for (int j = 0; j < 8; ++j)
                        v[j] = (cc > 0u) ? funkey(f2k[(size_t)rr * 32 + (q - 12) * 8 + j]) : 0.0f;
                }
            }
            p0 = pk2(v[0], v[1]); p1 = pk2(v[2], v[3]); p2 = pk2(v[4], v[5]); p3 = pk2(v[6], v[7]);
        }
        *(uint4*)(X + el * 136 + q * 8) = make_uint4(p0, p1, p2, p3);
    }
    auto stage = [&](unsigned off, int n) {
        for (int i = tid * 8; i < n; i += THREADS * 8)
            *(uint4*)(Wl + i) = *(const uint4*)(wts + off + i);
    };
    stage(OW_RO0, 8704);
    __syncthreads();
    f32x4 acc[1][4];
    gemm_core<1, 4, 4, 136, 136>(X, Wl, b0, 64, wv, lane, acc);
    writeback<1, 4, 136>(X, acc, wv, lane);
    __syncthreads(); stage(OW_RO1, 4608); __syncthreads();
    gemm_core<1, 4, 2, 136, 72>(X, Wl, b1, 64, wv, lane, acc);
    writeback<1, 4, 136>(X, acc, wv, lane);
    __syncthreads(); stage(OW_RO2, 4608); __syncthreads();
    gemm_core<1, 4, 2, 136, 72>(X, Wl, b2, 64, wv, lane, acc);
    writeback<1, 4, 136>(X, acc, wv, lane);
    __syncthreads(); stage(OW_RO3, 4608); __syncthreads();
    gemm_core<1, 4, 2, 136, 72>(X, Wl, b3, 64, wv, lane, acc);
    const int r = lane & 15, kg = lane >> 4;
#pragma unroll
    for (int nt = 0; nt < 4; ++nt)
#pragma unroll
        for (int q = 0; q < 4; ++q)
            out[(size_t)(NOUT_BASE + rbase + wv * 16 + kg * 4 + q) * 64 + nt * 16 + r] = acc[0][nt][q];
}

extern "C" void kernel_launch(void* const* d_in, const int* in_sizes, int n_in,
                              void* d_out, int out_size, void* d_ws, size_t ws_size,
                              hipStream_t stream) {
    const float* nf     = (const float*)d_in[0];
    const float* ef_out = (const float*)d_in[1];
    const float* ef_in  = (const float*)d_in[2];
    const float* o2i_w[5] = {(const float*)d_in[3], (const float*)d_in[5], (const float*)d_in[7], (const float*)d_in[9], (const float*)d_in[11]};
    const float* o2i_b[5] = {(const float*)d_in[4], (const float*)d_in[6], (const float*)d_in[8], (const float*)d_in[10], (const float*)d_in[12]};
    const float* i2o_w[4] = {(const float*)d_in[13], (const float*)d_in[15], (const float*)d_in[17], (const float*)d_in[19]};
    const float* i2o_b[4] = {(const float*)d_in[14], (const float*)d_in[16], (const float*)d_in[18], (const float*)d_in[20]};
    const float* ri_w[4]  = {(const float*)d_in[21], (const float*)d_in[23], (const float*)d_in[25], (const float*)d_in[27]};
    const float* ri_b[4]  = {(const float*)d_in[22], (const float*)d_in[24], (const float*)d_in[26], (const float*)d_in[28]};
    const float* ro_w[4]  = {(const float*)d_in[29], (const float*)d_in[31], (const float*)d_in[33], (const float*)d_in[35]};
    const float* ro_b[4]  = {(const float*)d_in[30], (const float*)d_in[32], (const float*)d_in[34], (const float*)d_in[36]};
    const int* src_out  = (const int*)d_in[37];
    const int* dst_out  = (const int*)d_in[38];
    const int* src_in   = (const int*)d_in[39];
    const int* dst_in   = (const int*)d_in[40];

    unsigned* ws    = (unsigned*)d_ws;
    float*    nfi   = (float*)(ws + OFF_NFI);
    float*    f1s   = (float*)(ws + OFF_F1);
    unsigned* f2k   = ws + OFF_F2;
    unsigned* hpo   = ws + OFF_HPO;
    unsigned* hpi   = ws + OFF_HPI;
    unsigned* cnt   = ws + OFF_CNT;
    unsigned* cnto  = ws + OFF_CNTO;
    unsigned* ctro  = ws + OFF_CTRO;
    unsigned* ctri  = ws + OFF_CTRI;
    float*    bvec  = (float*)(ws + OFF_BVEC);
    unsigned* opo   = ws + OFF_OPO;
    unsigned* opi   = ws + OFF_OPI;
    uint2*    lsto  = (uint2*)(ws + OFF_LISTO);
    uint2*    lsti  = (uint2*)(ws + OFF_LISTI);
    unsigned short* wts = (unsigned short*)(ws + OFF_WB);
    unsigned short* nfb = (unsigned short*)(ws + OFF_NFB);

    hipMemsetAsync(d_ws, 0, OFF_ZEND * sizeof(unsigned), stream);
    hipMemsetAsync((char*)d_out + (size_t)NIN * 64 * sizeof(float), 0,
                   (size_t)(NOUT_BASE - NIN) * 64 * sizeof(float), stream);

    WTab t;
    t.d[0]  = {o2i_w[0], 144,  64, 168,  64, OW_O2I0};
    t.d[1]  = {o2i_w[1],  64,  64,  72,  64, OW_O2I1};
    t.d[2]  = {o2i_w[2],  64,  64,  72,  64, OW_O2I2};
    t.d[3]  = {o2i_w[3],  64,  64,  72,  64, OW_O2I3};
    t.d[4]  = {i2o_w[0], 144,  64, 168,  64, OW_I2O0};
    t.d[5]  = {i2o_w[1],  64,  64,  72,  64, OW_I2O1};
    t.d[6]  = {i2o_w[2],  64,  64,  72,  64, OW_I2O2};
    t.d[7]  = {i2o_w[3],  64,  65,  72,  80, OW_I2O3};
    t.d[8]  = {ri_w[0],   64,  64,  72,  64, OW_RI0};   // nf part only (first 64 rows)
    t.d[9]  = {ri_w[1],   64,  64,  72,  64, OW_RI1};
    t.d[10] = {ri_w[2],   64,  64,  72,  64, OW_RI2};
    t.d[11] = {ri_w[3],   64,  64,  72,  64, OW_RI3};
    t.d[12] = {ro_w[0],  128,  64, 136,  64, OW_RO0};
    t.d[13] = {ro_w[1],   64,  64,  72,  64, OW_RO1};
    t.d[14] = {ro_w[2],   64,  64,  72,  64, OW_RO2};
    t.d[15] = {ro_w[3],   64,  64,  72,  64, OW_RO3};
    convert_w<<<dim3(50, 16), THREADS, 0, stream>>>(t, wts);
    compose_k<<<17, THREADS, 0, stream>>>(o2i_w[4], ri_w[0], o2i_b[4], wts, bvec);
    conv_nf_k<<<(N_NODES * 8 + THREADS - 1) / THREADS, THREADS, 0, stream>>>(nf, nfb);

    hist_k<<<N_EDGES / THREADS, THREADS, 0, stream>>>(dst_out, dst_in, hpo, hpi);
    scan2_k<<<2, 1024, 0, stream>>>(hpo, hpi, opo, opi, cnto, cnt, ctro, ctri);
    emit_k<<<N_EDGES / THREADS, THREADS, 0, stream>>>(
        src_out, dst_out, src_in, dst_in, opo, opi, lsto, lsti);

    edge_out_mfma<<<512, 512, 0, stream>>>(
        nfb, ef_out, lsto, ctro, wts,
        o2i_b[0], o2i_b[1], o2i_b[2], o2i_b[3], nfi);

    edge_in_mfma<<<512, 512, 0, stream>>>(
        nfb, ef_in, lsti, ctri, wts,
        i2o_b[0], i2o_b[1], i2o_b[2], i2o_b[3], f1s, f2k);

    node_ri_mfma<<<NIN / 64, THREADS, 0, stream>>>(
        nfb, nfi, cnto, bvec, wts, ri_b[0], ri_b[1], ri_b[2], ri_b[3], (float*)d_out);

    node_ro_mfma<<<NOUT / 64, THREADS, 0, stream>>>(
        nf, f1s, f2k, cnt, wts, ro_b[0], ro_b[1], ro_b[2], ro_b[3], (float*)d_out);
}

// Round 19
// 293.545 us; speedup vs baseline: 1.4292x; 1.4292x over previous
//
#include <hip/hip_runtime.h>
#include <cmath>

#define THREADS 256

static constexpr int N_NODES   = 100000;
static constexpr int N_EDGES   = 800000;
static constexpr int NIN       = 40000;   // input_mask: n < NIN
static constexpr int NOUT_BASE = 60000;   // output_mask: n >= NOUT_BASE
static constexpr int NOUT      = 40000;
static constexpr int LIST_CAP  = 400000;
static constexpr int PAD       = 16;      // u32 per bin (64B line) for contention-free atomics

// ---- workspace layout (32-bit words), ~45 MB ----
static constexpr size_t OFF_NFI   = 0;                                // 40000*64 f32 (pre-composed ri-l0 sums)
static constexpr size_t OFF_F1    = OFF_NFI   + (size_t)NIN  * 64;    // 40000*32 f32
static constexpr size_t OFF_F2    = OFF_F1    + (size_t)NOUT * 32;    // 40000*32 u32 keys
static constexpr size_t OFF_HPO   = OFF_F2    + (size_t)NOUT * 32;    // 40000*PAD u32 padded hist (o)
static constexpr size_t OFF_HPI   = OFF_HPO   + (size_t)NIN  * PAD;   // 40000*PAD u32 padded hist (i)
static constexpr size_t OFF_ZEND  = OFF_HPI   + (size_t)NOUT * PAD;   // zeroed region end
static constexpr size_t OFF_CNT   = OFF_ZEND;                         // 40000 u32 (dst_in deg, final_k-written)
static constexpr size_t OFF_CNTO  = OFF_CNT   + NOUT;                 // 40000 u32 (dst_out deg)
static constexpr size_t OFF_CTRO  = OFF_CNTO  + NIN;                  // 1
static constexpr size_t OFF_CTRI  = OFF_CTRO  + 1;                    // 1
static constexpr size_t OFF_BVEC  = OFF_CTRI  + 1;                    // 64 f32 (b4 @ Wr)
static constexpr size_t OFF_PSUM  = OFF_BVEC + 64;                    // [2][64] u32 block sums
static constexpr size_t OFF_PBASE = OFF_PSUM + 128;                   // [2][64] u32 block bases
static constexpr size_t OFF_OPO   = OFF_PBASE + 128;                  // 40000*PAD u32 padded offs (o)
static constexpr size_t OFF_OPI   = OFF_OPO + (size_t)NIN * PAD;      // 40000*PAD u32 padded offs (i)
static constexpr size_t OFF_LISTO = (OFF_OPI + (size_t)NOUT * PAD + 1) & ~(size_t)1; // LIST_CAP uint2
static constexpr size_t OFF_LISTI = OFF_LISTO + 2 * (size_t)LIST_CAP; // LIST_CAP uint2
static constexpr size_t OFF_WB    = (OFF_LISTI + 2 * (size_t)LIST_CAP + 3) & ~(size_t)3;  // 47936 u32
static constexpr size_t OFF_NFB   = OFF_WB + 47936;                   // nf bf16: 1.6M u32

// converted-weight offsets (ushort units). [n][k] layout, strides = Kp+8 (bank pad)
static constexpr unsigned OW_O2I0  = 0;       // 64 x 168
static constexpr unsigned OW_O2I1  = 10752;   // 64 x 72
static constexpr unsigned OW_O2I2  = 15360;
static constexpr unsigned OW_O2I3  = 19968;
static constexpr unsigned OW_O2I4C = 24576;   // 64 x 72  (composed o2i_w4 @ ri_w0[64:192])
static constexpr unsigned OW_I2O0  = 29184;   // 64 x 168
static constexpr unsigned OW_I2O1  = 39936;
static constexpr unsigned OW_I2O2  = 44544;
static constexpr unsigned OW_I2O3  = 49152;   // 80 x 72 (N=65 padded)
static constexpr unsigned OW_RI0   = 54912;   // 64 x 72 (nf part only: ri_w0[0:64])
static constexpr unsigned OW_RI1   = 59520;
static constexpr unsigned OW_RI2   = 64128;
static constexpr unsigned OW_RI3   = 68736;
static constexpr unsigned OW_RO0   = 73344;   // 64 x 136
static constexpr unsigned OW_RO1   = 82048;
static constexpr unsigned OW_RO2   = 86656;
static constexpr unsigned OW_RO3   = 91264;   // end 95872

typedef __attribute__((ext_vector_type(8))) short short8;
typedef __attribute__((ext_vector_type(4))) float f32x4;

__device__ __forceinline__ float lrelu(float x) { return x > 0.0f ? x : 0.2f * x; }

__device__ __forceinline__ unsigned short f2b(float f) {   // RNE f32->bf16
    unsigned u = __float_as_uint(f);
    return (unsigned short)((u + 0x7fffu + ((u >> 16) & 1u)) >> 16);
}
__device__ __forceinline__ unsigned pk2(float a, float b) {
    return (unsigned)f2b(a) | ((unsigned)f2b(b) << 16);
}
__device__ __forceinline__ short8 cvt8(const float4 va, const float4 vb) {
    union { uint4 u; short8 s; } t;
    t.u = make_uint4(pk2(va.x, va.y), pk2(va.z, va.w), pk2(vb.x, vb.y), pk2(vb.z, vb.w));
    return t.s;
}
__device__ __forceinline__ unsigned fkey(float f) {
    unsigned u = __float_as_uint(f);
    return (u & 0x80000000u) ? ~u : (u | 0x80000000u);
}
__device__ __forceinline__ float funkey(unsigned k) {
    return (k & 0x80000000u) ? __uint_as_float(k & 0x7fffffffu) : __uint_as_float(~k);
}
__device__ __forceinline__ uint2 packm(unsigned s, int d, int e) {
    return make_uint2(s | ((unsigned)(d & 0x7FFF) << 17),
                      (unsigned)e | (((unsigned)d >> 15) << 20));
}

// ---- block-cooperative gemm (node kernels) ----
template<int MT, int NT, int KT, int XSTR, int WSTR>
__device__ __forceinline__ void gemm_core(const unsigned short* X, const unsigned short* W,
                                          const float* bias, int biasN, int wv, int lane,
                                          f32x4 (&acc)[MT][NT]) {
    const int r = lane & 15, kg = lane >> 4;
    short8 a[MT][KT];
#pragma unroll
    for (int mt = 0; mt < MT; ++mt)
#pragma unroll
        for (int kk = 0; kk < KT; ++kk)
            a[mt][kk] = *(const short8*)(X + (wv * 16 * MT + mt * 16 + r) * XSTR + kk * 32 + kg * 8);
#pragma unroll
    for (int nt = 0; nt < NT; ++nt) {
        const int c = nt * 16 + r;
        const float bv = (c < biasN) ? bias[c] : 0.0f;
#pragma unroll
        for (int mt = 0; mt < MT; ++mt) acc[mt][nt] = (f32x4){bv, bv, bv, bv};
    }
#pragma unroll
    for (int kk = 0; kk < KT; ++kk)
#pragma unroll
        for (int nt = 0; nt < NT; ++nt) {
            short8 b = *(const short8*)(W + (nt * 16 + r) * WSTR + kk * 32 + kg * 8);
#pragma unroll
            for (int mt = 0; mt < MT; ++mt)
                acc[mt][nt] = __builtin_amdgcn_mfma_f32_16x16x32_bf16(a[mt][kk], b, acc[mt][nt], 0, 0, 0);
        }
}

template<int MT, int NT, int XSTR>
__device__ __forceinline__ void writeback(unsigned short* X, f32x4 (&acc)[MT][NT], int wv, int lane) {
    const int r = lane & 15, kg = lane >> 4;
#pragma unroll
    for (int mt = 0; mt < MT; ++mt)
#pragma unroll
        for (int nt = 0; nt < NT; ++nt)
#pragma unroll
            for (int q = 0; q < 4; ++q)
                X[(wv * 16 * MT + mt * 16 + kg * 4 + q) * XSTR + nt * 16 + r] = f2b(lrelu(acc[mt][nt][q]));
}

// ---- wave-local gemm (edge kernels) ----
template<int NT, int KT, int XSTR, int WSTR>
__device__ __forceinline__ void gemm_w1(const unsigned short* Xw, const unsigned short* W,
                                        const float* bv, int lane, f32x4 (&acc)[NT]) {
    const int r = lane & 15, kg = lane >> 4;
    short8 a[KT];
#pragma unroll
    for (int kk = 0; kk < KT; ++kk)
        a[kk] = *(const short8*)(Xw + r * XSTR + kk * 32 + kg * 8);
#pragma unroll
    for (int nt = 0; nt < NT; ++nt) acc[nt] = (f32x4){bv[nt], bv[nt], bv[nt], bv[nt]};
#pragma unroll
    for (int kk = 0; kk < KT; ++kk)
#pragma unroll
        for (int nt = 0; nt < NT; ++nt) {
            short8 b = *(const short8*)(W + (nt * 16 + r) * WSTR + kk * 32 + kg * 8);
            acc[nt] = __builtin_amdgcn_mfma_f32_16x16x32_bf16(a[kk], b, acc[nt], 0, 0, 0);
        }
}

template<int NT, int XSTR>
__device__ __forceinline__ void writeback_w1(unsigned short* Xw, f32x4 (&acc)[NT], int lane) {
    const int r = lane & 15, kg = lane >> 4;
#pragma unroll
    for (int nt = 0; nt < NT; ++nt)
#pragma unroll
        for (int q = 0; q < 4; ++q)
            Xw[(kg * 4 + q) * XSTR + nt * 16 + r] = f2b(lrelu(acc[nt][q]));
}

// ---- weight conversion ----
struct WDesc { const float* w; int K, N, stride, Np; unsigned off; };
struct WTab { WDesc d[16]; };

__global__ __launch_bounds__(THREADS)
void convert_w(WTab t, unsigned short* wts) {
    const WDesc d = t.d[blockIdx.y];
    const int idx = blockIdx.x * THREADS + threadIdx.x;
    const int tot = d.Np * d.stride;
    if (idx >= tot) return;
    const int n = idx / d.stride, k = idx - n * d.stride;
    const float v = (k < d.K && n < d.N) ? d.w[(size_t)k * d.N + n] : 0.0f;
    wts[d.off + idx] = f2b(v);
}

// ---- compose Wc = o2i_w4 (64x128) @ ri_w0[64:192] (128x64) -> bf16 [n][72]; bvec = b4 @ Wr ----
__global__ __launch_bounds__(THREADS)
void compose_k(const float* __restrict__ w4, const float* __restrict__ rw0,
               const float* __restrict__ b4, unsigned short* __restrict__ wts,
               float* __restrict__ bvec) {
    const int idx = blockIdx.x * THREADS + threadIdx.x;
    if (idx < 4096) {
        const int n = idx >> 6, k = idx & 63;
        float s = 0.0f;
        for (int j = 0; j < 128; ++j) s += w4[k * 128 + j] * rw0[(size_t)(64 + j) * 64 + n];
        wts[OW_O2I4C + n * 72 + k] = f2b(s);
    } else if (idx < 4160) {
        const int n = idx - 4096;
        float s = 0.0f;
        for (int j = 0; j < 128; ++j) s += b4[j] * rw0[(size_t)(64 + j) * 64 + n];
        bvec[n] = s;
    }
}

// ---- nf -> bf16 table ----
__global__ __launch_bounds__(THREADS)
void conv_nf_k(const float* __restrict__ nf, unsigned short* __restrict__ nfb) {
    const int i = blockIdx.x * THREADS + threadIdx.x;
    if (i >= N_NODES * 8) return;
    const float4 va = ((const float4*)nf)[i * 2], vb = ((const float4*)nf)[i * 2 + 1];
    *(uint4*)(nfb + (size_t)i * 8) =
        make_uint4(pk2(va.x, va.y), pk2(va.z, va.w), pk2(vb.x, vb.y), pk2(vb.z, vb.w));
}

// ---- counting sort phase 1: padded per-dst histograms (1 bin per 64B line) ----
__global__ __launch_bounds__(THREADS)
void hist_k(const int* __restrict__ dst_out, const int* __restrict__ dst_in,
            unsigned* __restrict__ hpo, unsigned* __restrict__ hpi) {
    const int e = blockIdx.x * THREADS + threadIdx.x;   // grid covers N_EDGES exactly
    const int d0 = dst_out[e];
    if (d0 < NIN) atomicAdd(hpo + (size_t)d0 * PAD, 1u);
    const int d1 = dst_in[e];
    if (d1 >= NOUT_BASE) atomicAdd(hpi + (size_t)(d1 - NOUT_BASE) * PAD, 1u);
}

// ---- scan step A: per-block (1000-bin) sums, 40x2 blocks ----
__global__ __launch_bounds__(THREADS)
void partial_k(const unsigned* __restrict__ hpo, const unsigned* __restrict__ hpi,
               unsigned* __restrict__ psum) {
    const unsigned* h = (blockIdx.y == 0) ? hpo : hpi;
    const int base = blockIdx.x * 1000;
    const int tid = threadIdx.x, lane = tid & 63, wv = tid >> 6;
    unsigned s = 0;
    for (int i = base + tid; i < base + 1000; i += THREADS) s += h[(size_t)i * PAD];
#pragma unroll
    for (int d = 1; d < 64; d <<= 1) s += __shfl_xor(s, d);
    __shared__ unsigned wsv[4];
    if (lane == 0) wsv[wv] = s;
    __syncthreads();
    if (tid == 0) psum[blockIdx.y * 64 + blockIdx.x] = wsv[0] + wsv[1] + wsv[2] + wsv[3];
}

// ---- scan step B: scan the 40 block sums per list (1 block) ----
__global__ __launch_bounds__(128)
void scan_ps_k(const unsigned* __restrict__ psum, unsigned* __restrict__ pbase,
               unsigned* __restrict__ ctro, unsigned* __restrict__ ctri) {
    const int lane = threadIdx.x & 63;
    const int list = threadIdx.x >> 6;
    const unsigned v = (lane < 40) ? psum[list * 64 + lane] : 0u;
    unsigned incl = v;
#pragma unroll
    for (int d = 1; d < 64; d <<= 1) { unsigned t = __shfl_up(incl, d); if (lane >= d) incl += t; }
    pbase[list * 64 + lane] = incl - v;
    if (lane == 63) { if (list == 0) *ctro = incl; else *ctri = incl; }
}

// ---- scan step C: block-local exclusive scan -> padded offs + dense counts ----
__global__ __launch_bounds__(THREADS)
void final_k(const unsigned* __restrict__ hpo, const unsigned* __restrict__ hpi,
             const unsigned* __restrict__ pbase,
             unsigned* __restrict__ opo, unsigned* __restrict__ opi,
             unsigned* __restrict__ cnto, unsigned* __restrict__ cnt) {
    const bool isO = (blockIdx.y == 0);
    const unsigned* h = isO ? hpo : hpi;
    unsigned* o  = isO ? opo : opi;
    unsigned* cc = isO ? cnto : cnt;
    const int base = blockIdx.x * 1000;
    const int tid = threadIdx.x, lane = tid & 63, wv = tid >> 6;
    unsigned c[4] = {0, 0, 0, 0};
    unsigned s = 0;
    if (tid < 250) {
#pragma unroll
        for (int j = 0; j < 4; ++j) { c[j] = h[(size_t)(base + tid * 4 + j) * PAD]; s += c[j]; }
    }
    unsigned incl = s;
#pragma unroll
    for (int d = 1; d < 64; d <<= 1) { unsigned v = __shfl_up(incl, d); if (lane >= d) incl += v; }
    __shared__ unsigned wsum[4], woff[4];
    if (lane == 63) wsum[wv] = incl;
    __syncthreads();
    if (tid < 4) {
        unsigned v = wsum[tid], sc = v;
#pragma unroll
        for (int d = 1; d < 4; d <<= 1) { unsigned t2 = __shfl_up(sc, d); if (tid >= d) sc += t2; }
        woff[tid] = sc - v;
    }
    __syncthreads();
    unsigned run = pbase[blockIdx.y * 64 + blockIdx.x] + woff[wv] + incl - s;
    if (tid < 250) {
#pragma unroll
        for (int j = 0; j < 4; ++j) {
            const int i = base + tid * 4 + j;
            cc[i] = c[j];
            o[(size_t)i * PAD] = run;
            run += c[j];
        }
    }
}

// ---- counting sort phase 3: emit dst-sorted packed lists {src,dst,e} (padded offset bins) ----
__global__ __launch_bounds__(THREADS)
void emit_k(const int* __restrict__ src_out, const int* __restrict__ dst_out,
            const int* __restrict__ src_in, const int* __restrict__ dst_in,
            unsigned* __restrict__ opo, unsigned* __restrict__ opi,
            uint2* __restrict__ listo, uint2* __restrict__ listi) {
    const int e = blockIdx.x * THREADS + threadIdx.x;
    const int d0 = dst_out[e];
    if (d0 < NIN) {
        const unsigned p = atomicAdd(opo + (size_t)d0 * PAD, 1u);
        if (p < (unsigned)LIST_CAP) listo[p] = packm((unsigned)src_out[e], d0, e);
    }
    const int d1 = dst_in[e];
    if (d1 >= NOUT_BASE) {
        const unsigned p = atomicAdd(opi + (size_t)(d1 - NOUT_BASE) * PAD, 1u);
        if (p < (unsigned)LIST_CAP) listi[p] = packm((unsigned)src_in[e], d1, e);
    }
}

// gather layer-0 A-fragments: src/dst rows from bf16 table, ef from f32
__device__ __forceinline__ void gather_a(short8 (&a)[5], const unsigned short* nfb, const float* ef,
                                         int e16, int s16, int d16, int kg) {
    const short8 z = {0, 0, 0, 0, 0, 0, 0, 0};
    if (e16 >= 0) {
        const unsigned short* ps = nfb + (size_t)s16 * 64 + kg * 8;
        const unsigned short* pd = nfb + (size_t)d16 * 64 + kg * 8;
        a[0] = *(const short8*)ps;
        a[1] = *(const short8*)(ps + 32);
        a[2] = *(const short8*)pd;
        a[3] = *(const short8*)(pd + 32);
        if (kg < 2) {
            const float* pe = ef + (size_t)e16 * 16 + kg * 8;
            a[4] = cvt8(((const float4*)pe)[0], ((const float4*)pe)[1]);
        } else a[4] = z;
    } else { a[0] = z; a[1] = z; a[2] = z; a[3] = z; a[4] = z; }
}

// ---- o2i edge MLP: composed last layer (64-wide), dst-sorted run-aggregated scatter ----
__global__ __launch_bounds__(512, 4)
void edge_out_mfma(const unsigned short* __restrict__ nfb, const float* __restrict__ ef,
                   const uint2* __restrict__ list, const unsigned* __restrict__ counter,
                   const unsigned short* __restrict__ wts,
                   const float* __restrict__ b0, const float* __restrict__ b1,
                   const float* __restrict__ b2, const float* __restrict__ b3,
                   float* __restrict__ nfi) {
    __shared__ unsigned short W[24576];     // layers 0-3
    __shared__ unsigned short X[128 * 72];
    const int tid = threadIdx.x, lane = tid & 63, wv = tid >> 6;
    const int r = lane & 15, kg = lane >> 4;
    for (int i = tid * 8; i < 24576; i += 512 * 8)
        *(uint4*)(W + i) = *(const uint4*)(wts + OW_O2I0 + i);
    float bv0[4], bv1[4], bv2[4], bv3[4];
    const float bz[4] = {0.0f, 0.0f, 0.0f, 0.0f};
#pragma unroll
    for (int nt = 0; nt < 4; ++nt) {
        bv0[nt] = b0[nt * 16 + r]; bv1[nt] = b1[nt * 16 + r];
        bv2[nt] = b2[nt * 16 + r]; bv3[nt] = b3[nt * 16 + r];
    }
    unsigned short* Xw = X + wv * 16 * 72;
    const unsigned short* W4C = wts + OW_O2I4C;   // 9.2KB composed weights, L1-resident
    const unsigned total = *counter;
    const unsigned nchunks = (total + 15) >> 4;
    __syncthreads();

    for (unsigned c = blockIdx.x * 8 + wv; c < nchunks; c += (unsigned)gridDim.x * 8) {
        const unsigned ebase = c << 4;
        int my_e = -1, my_s = 0, my_d = -1;
        if (lane < 16 && ebase + (unsigned)lane < total) {
            const uint2 m = list[ebase + lane];
            my_s = (int)(m.x & 0x1FFFFu);
            my_d = (int)(((m.x >> 17) & 0x7FFFu) | (((m.y >> 20) & 3u) << 15));
            my_e = (int)(m.y & 0xFFFFFu);
        }
        const int e16 = __shfl(my_e, r), s16 = __shfl(my_s, r), d16 = __shfl(my_d, r);
        short8 a[5];
        gather_a(a, nfb, ef, e16, s16, d16, kg);
        f32x4 acc[4];
#pragma unroll
        for (int nt = 0; nt < 4; ++nt) acc[nt] = (f32x4){bv0[nt], bv0[nt], bv0[nt], bv0[nt]};
#pragma unroll
        for (int kk = 0; kk < 5; ++kk)
#pragma unroll
            for (int nt = 0; nt < 4; ++nt) {
                short8 b = *(const short8*)(W + (nt * 16 + r) * 168 + kk * 32 + kg * 8);
                acc[nt] = __builtin_amdgcn_mfma_f32_16x16x32_bf16(a[kk], b, acc[nt], 0, 0, 0);
            }
        writeback_w1<4, 72>(Xw, acc, lane);
        gemm_w1<4, 2, 72, 72>(Xw, W + 10752, bv1, lane, acc); writeback_w1<4, 72>(Xw, acc, lane);
        gemm_w1<4, 2, 72, 72>(Xw, W + 15360, bv2, lane, acc); writeback_w1<4, 72>(Xw, acc, lane);
        gemm_w1<4, 2, 72, 72>(Xw, W + 19968, bv3, lane, acc); writeback_w1<4, 72>(Xw, acc, lane);
        f32x4 acc4[4];
        gemm_w1<4, 2, 72, 72>(Xw, W4C, bz, lane, acc4);
        // per-kg run-aggregated scatter-add (sorted list -> runs aggregate; 4 lines per flush)
        int re[4], rd[4];
#pragma unroll
        for (int q = 0; q < 4; ++q) {
            re[q] = __shfl(my_e, kg * 4 + q);
            rd[q] = __shfl(my_d, kg * 4 + q);
        }
        float s[4];
        int cur = -1;
#pragma unroll
        for (int q = 0; q < 4; ++q) {
            if (re[q] < 0) break;
            if (rd[q] != cur) {
                if (cur >= 0) {
                    float* p = nfi + (size_t)cur * 64;
#pragma unroll
                    for (int nt = 0; nt < 4; ++nt) atomicAdd(p + nt * 16 + r, s[nt]);
                }
                cur = rd[q];
#pragma unroll
                for (int nt = 0; nt < 4; ++nt) s[nt] = acc4[nt][q];
            } else {
#pragma unroll
                for (int nt = 0; nt < 4; ++nt) s[nt] += acc4[nt][q];
            }
        }
        if (cur >= 0) {
            float* p = nfi + (size_t)cur * 64;
#pragma unroll
            for (int nt = 0; nt < 4; ++nt) atomicAdd(p + nt * 16 + r, s[nt]);
        }
    }
}

// ---- i2o edge MLP: dst-sorted run-aggregated gated scatter ----
__global__ __launch_bounds__(512, 4)
void edge_in_mfma(const unsigned short* __restrict__ nfb, const float* __restrict__ ef,
                  const uint2* __restrict__ list, const unsigned* __restrict__ counter,
                  const unsigned short* __restrict__ wts,
                  const float* __restrict__ b0, const float* __restrict__ b1,
                  const float* __restrict__ b2, const float* __restrict__ b3,
                  float* __restrict__ f1s, unsigned* __restrict__ f2k) {
    __shared__ unsigned short W[25728];
    __shared__ unsigned short X[128 * 72];
    const int tid = threadIdx.x, lane = tid & 63, wv = tid >> 6;
    const int r = lane & 15, kg = lane >> 4;
    for (int i = tid * 8; i < 25728; i += 512 * 8)
        *(uint4*)(W + i) = *(const uint4*)(wts + OW_I2O0 + i);
    float bv0[4], bv1[4], bv2[4], bv3[5];
#pragma unroll
    for (int nt = 0; nt < 4; ++nt) {
        bv0[nt] = b0[nt * 16 + r]; bv1[nt] = b1[nt * 16 + r]; bv2[nt] = b2[nt * 16 + r];
        bv3[nt] = b3[nt * 16 + r];
    }
    bv3[4] = (r == 0) ? b3[64] : 0.0f;
    unsigned short* Xw = X + wv * 16 * 72;
    const unsigned total = *counter;
    const unsigned nchunks = (total + 15) >> 4;
    bool valid[5], isadd[5];
#pragma unroll
    for (int nt = 0; nt < 5; ++nt) {
        const int cc = nt * 16 + r;
        valid[nt] = (cc >= 1 && cc <= 64);
        isadd[nt] = (cc <= 32);
    }
    __syncthreads();

    for (unsigned c = blockIdx.x * 8 + wv; c < nchunks; c += (unsigned)gridDim.x * 8) {
        const unsigned ebase = c << 4;
        int my_e = -1, my_s = 0, my_d = -1;
        if (lane < 16 && ebase + (unsigned)lane < total) {
            const uint2 m = list[ebase + lane];
            my_s = (int)(m.x & 0x1FFFFu);
            my_d = (int)(((m.x >> 17) & 0x7FFFu) | (((m.y >> 20) & 3u) << 15));
            my_e = (int)(m.y & 0xFFFFFu);
        }
        const int e16 = __shfl(my_e, r), s16 = __shfl(my_s, r), d16 = __shfl(my_d, r);
        short8 a[5];
        gather_a(a, nfb, ef, e16, s16, d16, kg);
        f32x4 acc[4];
#pragma unroll
        for (int nt = 0; nt < 4; ++nt) acc[nt] = (f32x4){bv0[nt], bv0[nt], bv0[nt], bv0[nt]};
#pragma unroll
        for (int kk = 0; kk < 5; ++kk)
#pragma unroll
            for (int nt = 0; nt < 4; ++nt) {
                short8 b = *(const short8*)(W + (nt * 16 + r) * 168 + kk * 32 + kg * 8);
                acc[nt] = __builtin_amdgcn_mfma_f32_16x16x32_bf16(a[kk], b, acc[nt], 0, 0, 0);
            }
        writeback_w1<4, 72>(Xw, acc, lane);
        gemm_w1<4, 2, 72, 72>(Xw, W + 10752, bv1, lane, acc); writeback_w1<4, 72>(Xw, acc, lane);
        gemm_w1<4, 2, 72, 72>(Xw, W + 15360, bv2, lane, acc); writeback_w1<4, 72>(Xw, acc, lane);
        f32x4 acc5[5];
        gemm_w1<5, 2, 72, 72>(Xw, W + 19968, bv3, lane, acc5);
        int re[4], rd[4];
        float rgv[4];
#pragma unroll
        for (int q = 0; q < 4; ++q) {
            re[q]  = __shfl(my_e, kg * 4 + q);
            rd[q]  = __shfl(my_d, kg * 4 + q);
            rgv[q] = __shfl(acc5[4][q], lane & 48);
        }
        float s[5];
        int cur = -1;
        auto flush = [&](int d) {
            if (d < 0) return;
            const int rr = d - NOUT_BASE;
            if (valid[0]) atomicAdd(f1s + (size_t)rr * 32 + (r - 1), s[0]);
            if (valid[1]) atomicAdd(f1s + (size_t)rr * 32 + 15 + r, s[1]);
            if (valid[2]) {
                if (isadd[2]) atomicAdd(f1s + (size_t)rr * 32 + 31, s[2]);
                else          atomicMax(f2k + (size_t)rr * 32 + (r - 1), fkey(s[2]));
            }
            if (valid[3]) atomicMax(f2k + (size_t)rr * 32 + 15 + r, fkey(s[3]));
            if (valid[4]) atomicMax(f2k + (size_t)rr * 32 + 31, fkey(s[4]));
        };
#pragma unroll
        for (int q = 0; q < 4; ++q) {
            if (re[q] < 0) break;
            const float kgv = 1.0f / (1.0f + expf(-rgv[q]));
            if (rd[q] != cur) {
                flush(cur);
                cur = rd[q];
#pragma unroll
                for (int nt = 0; nt < 5; ++nt) s[nt] = acc5[nt][q] * kgv;
            } else {
#pragma unroll
                for (int nt = 0; nt < 5; ++nt) {
                    const float v = acc5[nt][q] * kgv;
                    s[nt] = isadd[nt] ? s[nt] + v : fmaxf(s[nt], v);
                }
            }
        }
        flush(cur);
    }
}

// ---- ri node MLP: layer0 = nf@W0a + nfi_s + cnt*bvec + b0, then 64->64->64->64 ----
__global__ __launch_bounds__(THREADS)
void node_ri_mfma(const unsigned short* __restrict__ nfb, const float* __restrict__ nfi,
                  const unsigned* __restrict__ cnto, const float* __restrict__ bvec,
                  const unsigned short* __restrict__ wts,
                  const float* __restrict__ b0, const float* __restrict__ b1,
                  const float* __restrict__ b2, const float* __restrict__ b3,
                  float* __restrict__ out) {
    __shared__ unsigned short X[64 * 72];
    __shared__ unsigned short Wl[4608];
    const int tid = threadIdx.x, lane = tid & 63, wv = tid >> 6;
    const int base = blockIdx.x * 64;
    for (int i = tid; i < 64 * 8; i += THREADS) {
        const int el = i >> 3, q = i & 7;
        *(uint4*)(X + el * 72 + q * 8) = *(const uint4*)(nfb + (size_t)(base + el) * 64 + q * 8);
    }
    auto stage = [&](unsigned off) {
        for (int i = tid * 8; i < 4608; i += THREADS * 8)
            *(uint4*)(Wl + i) = *(const uint4*)(wts + off + i);
    };
    stage(OW_RI0);
    __syncthreads();
    const int r = lane & 15, kg = lane >> 4;
    f32x4 acc[1][4];
    gemm_core<1, 4, 2, 72, 72>(X, Wl, b0, 64, wv, lane, acc);
    {
        float bvv[4];
#pragma unroll
        for (int nt = 0; nt < 4; ++nt) bvv[nt] = bvec[nt * 16 + r];
#pragma unroll
        for (int q = 0; q < 4; ++q) {
            const int node = base + wv * 16 + kg * 4 + q;
            const float cf = (float)cnto[node];
#pragma unroll
            for (int nt = 0; nt < 4; ++nt)
                acc[0][nt][q] += nfi[(size_t)node * 64 + nt * 16 + r] + cf * bvv[nt];
        }
    }
    writeback<1, 4, 72>(X, acc, wv, lane);
    __syncthreads(); stage(OW_RI1); __syncthreads();
    gemm_core<1, 4, 2, 72, 72>(X, Wl, b1, 64, wv, lane, acc);
    writeback<1, 4, 72>(X, acc, wv, lane);
    __syncthreads(); stage(OW_RI2); __syncthreads();
    gemm_core<1, 4, 2, 72, 72>(X, Wl, b2, 64, wv, lane, acc);
    writeback<1, 4, 72>(X, acc, wv, lane);
    __syncthreads(); stage(OW_RI3); __syncthreads();
    gemm_core<1, 4, 2, 72, 72>(X, Wl, b3, 64, wv, lane, acc);
#pragma unroll
    for (int nt = 0; nt < 4; ++nt)
#pragma unroll
        for (int q = 0; q < 4; ++q)
            out[(size_t)(base + wv * 16 + kg * 4 + q) * 64 + nt * 16 + r] = acc[0][nt][q];
}

// ---- ro node MLP (128->64->64->64->64), nodes [NOUT_BASE, N) ----
__global__ __launch_bounds__(THREADS)
void node_ro_mfma(const float* __restrict__ nf, const float* __restrict__ f1s,
                  const unsigned* __restrict__ f2k, const unsigned* __restrict__ cnt,
                  const unsigned short* __restrict__ wts,
                  const float* __restrict__ b0, const float* __restrict__ b1,
                  const float* __restrict__ b2, const float* __restrict__ b3,
                  float* __restrict__ out) {
    __shared__ unsigned short X[64 * 136];
    __shared__ unsigned short Wl[8704];
    const int tid = threadIdx.x, lane = tid & 63, wv = tid >> 6;
    const int rbase = blockIdx.x * 64;
    for (int i = tid; i < 64 * 17; i += THREADS) {
        const int el = i / 17, q = i - el * 17;
        const int rr = rbase + el;
        unsigned p0 = 0, p1 = 0, p2 = 0, p3 = 0;
        if (q < 16) {
            float v[8];
            if (q < 8) {
                const float* sp = nf + (size_t)(NOUT_BASE + rr) * 64 + q * 8;
                const float4 va = *(const float4*)sp, vb = *(const float4*)(sp + 4);
                v[0]=va.x; v[1]=va.y; v[2]=va.z; v[3]=va.w; v[4]=vb.x; v[5]=vb.y; v[6]=vb.z; v[7]=vb.w;
            } else {
                const unsigned cc = cnt[rr];
                if (q < 12) {
                    const float inv = 1.0f / fmaxf((float)cc, 1.0f);
#pragma unroll
                    for (int j = 0; j < 8; ++j) v[j] = f1s[(size_t)rr * 32 + (q - 8) * 8 + j] * inv;
                } else {
#pragma unroll
                    for (int j = 0; j < 8; ++j)
                        v[j] = (cc > 0u) ? funkey(f2k[(size_t)rr * 32 + (q - 12) * 8 + j]) : 0.0f;
                }
            }
            p0 = pk2(v[0], v[1]); p1 = pk2(v[2], v[3]); p2 = pk2(v[4], v[5]); p3 = pk2(v[6], v[7]);
        }
        *(uint4*)(X + el * 136 + q * 8) = make_uint4(p0, p1, p2, p3);
    }
    auto stage = [&](unsigned off, int n) {
        for (int i = tid * 8; i < n; i += THREADS * 8)
            *(uint4*)(Wl + i) = *(const uint4*)(wts + off + i);
    };
    stage(OW_RO0, 8704);
    __syncthreads();
    f32x4 acc[1][4];
    gemm_core<1, 4, 4, 136, 136>(X, Wl, b0, 64, wv, lane, acc);
    writeback<1, 4, 136>(X, acc, wv, lane);
    __syncthreads(); stage(OW_RO1, 4608); __syncthreads();
    gemm_core<1, 4, 2, 136, 72>(X, Wl, b1, 64, wv, lane, acc);
    writeback<1, 4, 136>(X, acc, wv, lane);
    __syncthreads(); stage(OW_RO2, 4608); __syncthreads();
    gemm_core<1, 4, 2, 136, 72>(X, Wl, b2, 64, wv, lane, acc);
    writeback<1, 4, 136>(X, acc, wv, lane);
    __syncthreads(); stage(OW_RO3, 4608); __syncthreads();
    gemm_core<1, 4, 2, 136, 72>(X, Wl, b3, 64, wv, lane, acc);
    const int r = lane & 15, kg = lane >> 4;
#pragma unroll
    for (int nt = 0; nt < 4; ++nt)
#pragma unroll
        for (int q = 0; q < 4; ++q)
            out[(size_t)(NOUT_BASE + rbase + wv * 16 + kg * 4 + q) * 64 + nt * 16 + r] = acc[0][nt][q];
}

extern "C" void kernel_launch(void* const* d_in, const int* in_sizes, int n_in,
                              void* d_out, int out_size, void* d_ws, size_t ws_size,
                              hipStream_t stream) {
    const float* nf     = (const float*)d_in[0];
    const float* ef_out = (const float*)d_in[1];
    const float* ef_in  = (const float*)d_in[2];
    const float* o2i_w[5] = {(const float*)d_in[3], (const float*)d_in[5], (const float*)d_in[7], (const float*)d_in[9], (const float*)d_in[11]};
    const float* o2i_b[5] = {(const float*)d_in[4], (const float*)d_in[6], (const float*)d_in[8], (const float*)d_in[10], (const float*)d_in[12]};
    const float* i2o_w[4] = {(const float*)d_in[13], (const float*)d_in[15], (const float*)d_in[17], (const float*)d_in[19]};
    const float* i2o_b[4] = {(const float*)d_in[14], (const float*)d_in[16], (const float*)d_in[18], (const float*)d_in[20]};
    const float* ri_w[4]  = {(const float*)d_in[21], (const float*)d_in[23], (const float*)d_in[25], (const float*)d_in[27]};
    const float* ri_b[4]  = {(const float*)d_in[22], (const float*)d_in[24], (const float*)d_in[26], (const float*)d_in[28]};
    const float* ro_w[4]  = {(const float*)d_in[29], (const float*)d_in[31], (const float*)d_in[33], (const float*)d_in[35]};
    const float* ro_b[4]  = {(const float*)d_in[30], (const float*)d_in[32], (const float*)d_in[34], (const float*)d_in[36]};
    const int* src_out  = (const int*)d_in[37];
    const int* dst_out  = (const int*)d_in[38];
    const int* src_in   = (const int*)d_in[39];
    const int* dst_in   = (const int*)d_in[40];

    unsigned* ws    = (unsigned*)d_ws;
    float*    nfi   = (float*)(ws + OFF_NFI);
    float*    f1s   = (float*)(ws + OFF_F1);
    unsigned* f2k   = ws + OFF_F2;
    unsigned* hpo   = ws + OFF_HPO;
    unsigned* hpi   = ws + OFF_HPI;
    unsigned* cnt   = ws + OFF_CNT;
    unsigned* cnto  = ws + OFF_CNTO;
    unsigned* ctro  = ws + OFF_CTRO;
    unsigned* ctri  = ws + OFF_CTRI;
    float*    bvec  = (float*)(ws + OFF_BVEC);
    unsigned* psum  = ws + OFF_PSUM;
    unsigned* pbase = ws + OFF_PBASE;
    unsigned* opo   = ws + OFF_OPO;
    unsigned* opi   = ws + OFF_OPI;
    uint2*    lsto  = (uint2*)(ws + OFF_LISTO);
    uint2*    lsti  = (uint2*)(ws + OFF_LISTI);
    unsigned short* wts = (unsigned short*)(ws + OFF_WB);
    unsigned short* nfb = (unsigned short*)(ws + OFF_NFB);

    hipMemsetAsync(d_ws, 0, OFF_ZEND * sizeof(unsigned), stream);
    hipMemsetAsync((char*)d_out + (size_t)NIN * 64 * sizeof(float), 0,
                   (size_t)(NOUT_BASE - NIN) * 64 * sizeof(float), stream);

    WTab t;
    t.d[0]  = {o2i_w[0], 144,  64, 168,  64, OW_O2I0};
    t.d[1]  = {o2i_w[1],  64,  64,  72,  64, OW_O2I1};
    t.d[2]  = {o2i_w[2],  64,  64,  72,  64, OW_O2I2};
    t.d[3]  = {o2i_w[3],  64,  64,  72,  64, OW_O2I3};
    t.d[4]  = {i2o_w[0], 144,  64, 168,  64, OW_I2O0};
    t.d[5]  = {i2o_w[1],  64,  64,  72,  64, OW_I2O1};
    t.d[6]  = {i2o_w[2],  64,  64,  72,  64, OW_I2O2};
    t.d[7]  = {i2o_w[3],  64,  65,  72,  80, OW_I2O3};
    t.d[8]  = {ri_w[0],   64,  64,  72,  64, OW_RI0};   // nf part only (first 64 rows)
    t.d[9]  = {ri_w[1],   64,  64,  72,  64, OW_RI1};
    t.d[10] = {ri_w[2],   64,  64,  72,  64, OW_RI2};
    t.d[11] = {ri_w[3],   64,  64,  72,  64, OW_RI3};
    t.d[12] = {ro_w[0],  128,  64, 136,  64, OW_RO0};
    t.d[13] = {ro_w[1],   64,  64,  72,  64, OW_RO1};
    t.d[14] = {ro_w[2],   64,  64,  72,  64, OW_RO2};
    t.d[15] = {ro_w[3],   64,  64,  72,  64, OW_RO3};
    convert_w<<<dim3(50, 16), THREADS, 0, stream>>>(t, wts);
    compose_k<<<17, THREADS, 0, stream>>>(o2i_w[4], ri_w[0], o2i_b[4], wts, bvec);
    conv_nf_k<<<(N_NODES * 8 + THREADS - 1) / THREADS, THREADS, 0, stream>>>(nf, nfb);

    hist_k<<<N_EDGES / THREADS, THREADS, 0, stream>>>(dst_out, dst_in, hpo, hpi);
    partial_k<<<dim3(40, 2), THREADS, 0, stream>>>(hpo, hpi, psum);
    scan_ps_k<<<1, 128, 0, stream>>>(psum, pbase, ctro, ctri);
    final_k<<<dim3(40, 2), THREADS, 0, stream>>>(hpo, hpi, pbase, opo, opi, cnto, cnt);
    emit_k<<<N_EDGES / THREADS, THREADS, 0, stream>>>(
        src_out, dst_out, src_in, dst_in, opo, opi, lsto, lsti);

    edge_out_mfma<<<512, 512, 0, stream>>>(
        nfb, ef_out, lsto, ctro, wts,
        o2i_b[0], o2i_b[1], o2i_b[2], o2i_b[3], nfi);

    edge_in_mfma<<<512, 512, 0, stream>>>(
        nfb, ef_in, lsti, ctri, wts,
        i2o_b[0], i2o_b[1], i2o_b[2], i2o_b[3], f1s, f2k);

    node_ri_mfma<<<NIN / 64, THREADS, 0, stream>>>(
        nfb, nfi, cnto, bvec, wts, ri_b[0], ri_b[1], ri_b[2], ri_b[3], (float*)d_out);

    node_ro_mfma<<<NOUT / 64, THREADS, 0, stream>>>(
        nf, f1s, f2k, cnt, wts, ro_b[0], ro_b[1], ro_b[2], ro_b[3], (float*)d_out);
}